// Round 10
// baseline (228.138 us; speedup 1.0000x reference)
//
#include <hip/hip_runtime.h>
#include <math.h>

#define SDIM 256
#define CH 5
#define ROWF (SDIM * CH)      // 1280 floats per image row
#define GRAYF 0.9999f         // 0.2989+0.5870+0.1140

// ONE fused kernel. 512 blocks: image b = bid&63, part p = bid>>6 (8 parts).
// Each block: (1) builds per-image resample weights, (2) computes the FULL
// per-image channel sums itself (redundant 8x, but L2-served: parts of image b
// share bid%8 == b%8 -> same XCD under round-robin dispatch), (3) derives the
// affine locally (no global sync / no workspace), (4) writes its 32 output rows.
__global__ __launch_bounds__(256) void aug_fused_kernel(
    const float* __restrict__ crops,
    const float* __restrict__ off_frac,
    const int*   __restrict__ crop_size,
    const int*   __restrict__ do_crop,
    const int*   __restrict__ flip,
    const int*   __restrict__ rot_k,
    const float* __restrict__ bright,
    const float* __restrict__ contrast,
    float* __restrict__ out)
{
    const int tid = threadIdx.x;
    const int b   = blockIdx.x & 63;   // image  (bid%8 == b%8 -> XCD locality)
    const int pp  = blockIdx.x >> 6;   // part 0..7 -> output rows pp*32..pp*32+31

    __shared__ __align__(16) float smem[28 * 260];   // stage / obuf union
    __shared__ __align__(16) float wyl[SDIM];
    __shared__ __align__(16) float wxl[SDIM];
    __shared__ float psum[4][CH];
    __shared__ float prm[2 * CH];

    const bool  docrop = do_crop[b] != 0;
    const float size_f = docrop ? (float)crop_size[b] : 256.0f;
    const float scale  = size_f * (1.0f / 256.0f);
    const float span   = 256.0f - size_f + 1.0f;
    const float off0   = docrop ? floorf(off_frac[2 * b + 0] * span) : 0.0f;
    const float off1   = docrop ? floorf(off_frac[2 * b + 1] * span) : 0.0f;
    const int   k      = rot_k[b] & 3;
    const bool  flp    = flip[b] != 0;

    // ---- per-image separable resample weights ----
    wyl[tid] = 0.0f;
    wxl[tid] = 0.0f;
    __syncthreads();
    {   // scatter (tid = output coordinate)
        const float cy = ((float)tid + 0.5f) * scale - 0.5f + off0;
        const float fl = floorf(cy);
        const float fy = cy - fl;
        const int r0 = min(max((int)fl, 0), 255);
        const int r1 = min(max((int)fl + 1, 0), 255);
        atomicAdd(&wyl[r0], 1.0f - fy);
        atomicAdd(&wyl[r1], fy);

        const float cx = ((float)tid + 0.5f) * scale - 0.5f + off1;
        const float fl2 = floorf(cx);
        const float fx  = cx - fl2;
        const int c0 = min(max((int)fl2, 0), 255);
        const int c1 = min(max((int)fl2 + 1, 0), 255);
        atomicAdd(&wxl[c0], 1.0f - fx);
        atomicAdd(&wxl[c1], fx);
    }
    __syncthreads();

    // ---- FULL-image weighted channel sums (sum(resample) separable form) ----
    // chunk m (0..16383): row r=m>>6 (wave-uniform), 4-pixel group t=m&63.
    const float* srcbase = crops + (size_t)b * SDIM * ROWF;
    float acc[5] = {0.0f, 0.0f, 0.0f, 0.0f, 0.0f};
    #pragma unroll 4
    for (int it = 0; it < 64; ++it) {
        const int m = it * 256 + tid;
        const int r = m >> 6;
        const int t = m & 63;
        const float4* p4 = reinterpret_cast<const float4*>(srcbase + r * ROWF + t * 20);
        const float4 q0 = p4[0], q1 = p4[1], q2 = p4[2], q3 = p4[3], q4 = p4[4];
        const float wr = wyl[r];
        const float4 wx = reinterpret_cast<const float4*>(wxl)[t];
        const float w0 = wx.x * wr, w1 = wx.y * wr, w2 = wx.z * wr, w3 = wx.w * wr;
        acc[0] += q0.x * w0; acc[1] += q0.y * w0; acc[2] += q0.z * w0; acc[3] += q0.w * w0;
        acc[4] += q1.x * w0; acc[0] += q1.y * w1; acc[1] += q1.z * w1; acc[2] += q1.w * w1;
        acc[3] += q2.x * w1; acc[4] += q2.y * w1; acc[0] += q2.z * w2; acc[1] += q2.w * w2;
        acc[2] += q3.x * w2; acc[3] += q3.y * w2; acc[4] += q3.z * w2; acc[0] += q3.w * w3;
        acc[1] += q4.x * w3; acc[2] += q4.y * w3; acc[3] += q4.z * w3; acc[4] += q4.w * w3;
    }

    const int lane = tid & 63;
    const int wv   = tid >> 6;
    #pragma unroll
    for (int ch = 0; ch < CH; ++ch) {
        float s = acc[ch];
        #pragma unroll
        for (int o = 32; o > 0; o >>= 1) s += __shfl_down(s, o, 64);
        if (lane == 0) psum[wv][ch] = s;
    }
    __syncthreads();
    if (tid < CH) {   // affine: out = v*aa + ab, derived locally
        const float s  = psum[0][tid] + psum[1][tid] + psum[2][tid] + psum[3][tid];
        const float m  = s * (1.0f / 65536.0f);
        const float co = contrast[b * CH + tid];
        const float br = bright[b * CH + tid];
        prm[tid]      = co * GRAYF;
        prm[CH + tid] = ((1.0f - co) * m + br) * GRAYF;
    }

    // ---- output phase: 8 groups of 4 rows (rows pp*32 .. pp*32+31) ----
    const int rr = tid >> 6;           // output row within group (wave-uniform)

    for (int og = 0; og < 8; ++og) {
        const int oi0 = pp * 32 + og * 4;
        __syncthreads();   // smem reuse guard (also publishes prm on first pass)

        float vout[20];    // vout[p*5+ch] for pixel oj = lane + 64p

        if ((k & 1) == 0) {
            // ---- even k: src row <- oi (wave-uniform), src col <- oj ----
            const int y_min = (k == 0) ? oi0 : 255 - (oi0 + 3);
            const float cymin = ((float)y_min + 0.5f) * scale - 0.5f + off0;
            const int rbase = (int)floorf(cymin);
            const int nst   = docrop ? 5 : 4;

            const float4* src4 = reinterpret_cast<const float4*>(srcbase);
            float4* dst4 = reinterpret_cast<float4*>(smem);
            for (int i = tid; i < nst * 320; i += 256) {
                const int w  = i / 320;
                const int f4 = i - w * 320;
                const int rc = min(max(rbase + w, 0), 255);
                dst4[i] = src4[rc * 320 + f4];
            }
            __syncthreads();

            const int oi = oi0 + rr;
            const int y  = (k == 0) ? oi : 255 - oi;

            if (!docrop) {
                const float* rb = smem + (y - rbase) * ROWF;
                #pragma unroll
                for (int p = 0; p < 4; ++p) {
                    const int oj = lane + 64 * p;
                    const int xf = (k == 0) ? oj : 255 - oj;
                    const int x  = flp ? 255 - xf : xf;
                    #pragma unroll
                    for (int ch = 0; ch < CH; ++ch) vout[p * 5 + ch] = rb[x * CH + ch];
                }
            } else {
                const float cy  = ((float)y + 0.5f) * scale - 0.5f + off0;
                const float flr = floorf(cy);
                const float fy  = cy - flr;
                const float* rbA = smem + ((int)flr - rbase) * ROWF;
                const float* rbB = rbA + ROWF;
                #pragma unroll
                for (int p = 0; p < 4; ++p) {
                    const int oj = lane + 64 * p;
                    const int xf = (k == 0) ? oj : 255 - oj;
                    const int x  = flp ? 255 - xf : xf;
                    const float cx  = ((float)x + 0.5f) * scale - 0.5f + off1;
                    const float fl2 = floorf(cx);
                    const float fx  = cx - fl2;
                    const int c0 = min(max((int)fl2, 0), 255);
                    const int c1 = min(max((int)fl2 + 1, 0), 255);
                    #pragma unroll
                    for (int ch = 0; ch < CH; ++ch) {
                        const float aV = rbA[c0 * CH + ch] + fx * (rbA[c1 * CH + ch] - rbA[c0 * CH + ch]);
                        const float dV = rbB[c0 * CH + ch] + fx * (rbB[c1 * CH + ch] - rbB[c0 * CH + ch]);
                        vout[p * 5 + ch] = aV + fy * (dV - aV);
                    }
                }
            }
        } else {
            // ---- odd k: src col <- oi (wave-uniform), src row <- oj ----
            const int xfA = (k == 1) ? 255 - oi0 : oi0;
            const int xfB = (k == 1) ? 255 - (oi0 + 3) : oi0 + 3;
            const int xA = flp ? 255 - xfA : xfA;
            const int xB = flp ? 255 - xfB : xfB;
            const int xmin = min(xA, xB);

            if (!docrop) {
                const int base4 = min((xmin * CH) & ~3, ROWF - 24);
                const float4* rp = reinterpret_cast<const float4*>(
                    srcbase + (size_t)tid * ROWF + base4);
                const float4 q0 = rp[0], q1 = rp[1], q2 = rp[2];
                const float4 q3 = rp[3], q4 = rp[4], q5 = rp[5];
                smem[ 0*260+tid]=q0.x; smem[ 1*260+tid]=q0.y; smem[ 2*260+tid]=q0.z; smem[ 3*260+tid]=q0.w;
                smem[ 4*260+tid]=q1.x; smem[ 5*260+tid]=q1.y; smem[ 6*260+tid]=q1.z; smem[ 7*260+tid]=q1.w;
                smem[ 8*260+tid]=q2.x; smem[ 9*260+tid]=q2.y; smem[10*260+tid]=q2.z; smem[11*260+tid]=q2.w;
                smem[12*260+tid]=q3.x; smem[13*260+tid]=q3.y; smem[14*260+tid]=q3.z; smem[15*260+tid]=q3.w;
                smem[16*260+tid]=q4.x; smem[17*260+tid]=q4.y; smem[18*260+tid]=q4.z; smem[19*260+tid]=q4.w;
                smem[20*260+tid]=q5.x; smem[21*260+tid]=q5.y; smem[22*260+tid]=q5.z; smem[23*260+tid]=q5.w;
                __syncthreads();

                const int oi = oi0 + rr;
                const int xf = (k == 1) ? 255 - oi : oi;
                const int x  = flp ? 255 - xf : xf;
                const int slotA = x * CH - base4;
                #pragma unroll
                for (int p = 0; p < 4; ++p) {
                    const int oj = lane + 64 * p;
                    const int y  = (k == 1) ? oj : 255 - oj;
                    #pragma unroll
                    for (int ch = 0; ch < CH; ++ch)
                        vout[p * 5 + ch] = smem[(slotA + ch) * 260 + y];
                }
            } else {
                const float cxmin = ((float)xmin + 0.5f) * scale - 0.5f + off1;
                const int cbase = (int)floorf(cxmin);
                const int base4 = (cbase * CH) & ~3;
                const bool fastp = (cbase >= 0) && (cbase + 4 <= 255) && (base4 >= 0) && (base4 + 28 <= ROWF);

                if (fastp) {
                    const float4* rp = reinterpret_cast<const float4*>(
                        srcbase + (size_t)tid * ROWF + base4);
                    const float4 q0 = rp[0], q1 = rp[1], q2 = rp[2], q3 = rp[3];
                    const float4 q4 = rp[4], q5 = rp[5], q6 = rp[6];
                    smem[ 0*260+tid]=q0.x; smem[ 1*260+tid]=q0.y; smem[ 2*260+tid]=q0.z; smem[ 3*260+tid]=q0.w;
                    smem[ 4*260+tid]=q1.x; smem[ 5*260+tid]=q1.y; smem[ 6*260+tid]=q1.z; smem[ 7*260+tid]=q1.w;
                    smem[ 8*260+tid]=q2.x; smem[ 9*260+tid]=q2.y; smem[10*260+tid]=q2.z; smem[11*260+tid]=q2.w;
                    smem[12*260+tid]=q3.x; smem[13*260+tid]=q3.y; smem[14*260+tid]=q3.z; smem[15*260+tid]=q3.w;
                    smem[16*260+tid]=q4.x; smem[17*260+tid]=q4.y; smem[18*260+tid]=q4.z; smem[19*260+tid]=q4.w;
                    smem[20*260+tid]=q5.x; smem[21*260+tid]=q5.y; smem[22*260+tid]=q5.z; smem[23*260+tid]=q5.w;
                    smem[24*260+tid]=q6.x; smem[25*260+tid]=q6.y; smem[26*260+tid]=q6.z; smem[27*260+tid]=q6.w;
                } else {
                    #pragma unroll
                    for (int w = 0; w < 28; ++w) {
                        const int f2 = base4 + w + ROWF;       // bias keeps div positive
                        const int c2 = f2 / 5;
                        const int ch = f2 - c2 * 5;
                        const int cc = min(max(c2 - 256, 0), 255);
                        smem[w * 260 + tid] = srcbase[(size_t)tid * ROWF + cc * CH + ch];
                    }
                }
                __syncthreads();

                const int oi = oi0 + rr;
                const int xf = (k == 1) ? 255 - oi : oi;
                const int x  = flp ? 255 - xf : xf;
                const float cx  = ((float)x + 0.5f) * scale - 0.5f + off1;
                const float fl2 = floorf(cx);
                const float fx  = cx - fl2;
                const int slotA = (int)fl2 * CH - base4;   // pre-clamp slot; content clamped
                const int slotB = slotA + CH;

                #pragma unroll
                for (int p = 0; p < 4; ++p) {
                    const int oj = lane + 64 * p;
                    const int y  = (k == 1) ? oj : 255 - oj;
                    const float cy  = ((float)y + 0.5f) * scale - 0.5f + off0;
                    const float flr = floorf(cy);
                    const float fy  = cy - flr;
                    const int r0 = min(max((int)flr, 0), 255);
                    const int r1 = min(max((int)flr + 1, 0), 255);
                    #pragma unroll
                    for (int ch = 0; ch < CH; ++ch) {
                        const float p00 = smem[(slotA + ch) * 260 + r0];
                        const float p01 = smem[(slotB + ch) * 260 + r0];
                        const float p10 = smem[(slotA + ch) * 260 + r1];
                        const float p11 = smem[(slotB + ch) * 260 + r1];
                        const float aV = p00 + fx * (p01 - p00);
                        const float dV = p10 + fx * (p11 - p10);
                        vout[p * 5 + ch] = aV + fy * (dV - aV);
                    }
                }
            }
        }

        // ---- fused affine + repack through LDS + dense float4 stores ----
        float aa[5], ab[5];
        #pragma unroll
        for (int ch = 0; ch < CH; ++ch) { aa[ch] = prm[ch]; ab[ch] = prm[CH + ch]; }
        #pragma unroll
        for (int p = 0; p < 4; ++p)
            #pragma unroll
            for (int ch = 0; ch < CH; ++ch)
                vout[p * 5 + ch] = vout[p * 5 + ch] * aa[ch] + ab[ch];

        __syncthreads();   // staging done; reuse smem as obuf[4][1280]
        #pragma unroll
        for (int p = 0; p < 4; ++p) {
            const int oj = lane + 64 * p;
            #pragma unroll
            for (int ch = 0; ch < CH; ++ch)
                smem[rr * ROWF + oj * CH + ch] = vout[p * 5 + ch];
        }
        __syncthreads();

        const float4* ob4 = reinterpret_cast<const float4*>(smem);
        float4* dst = reinterpret_cast<float4*>(out + ((size_t)b * SDIM + oi0) * ROWF);
        #pragma unroll
        for (int q = 0; q < 5; ++q) dst[q * 256 + tid] = ob4[q * 256 + tid];
    }
}

extern "C" void kernel_launch(void* const* d_in, const int* in_sizes, int n_in,
                              void* d_out, int out_size, void* d_ws, size_t ws_size,
                              hipStream_t stream) {
    const float* crops     = (const float*)d_in[0];
    const float* off_frac  = (const float*)d_in[1];
    const float* bright    = (const float*)d_in[2];
    const float* contrast  = (const float*)d_in[3];
    const int*   crop_size = (const int*)d_in[4];
    const int*   do_crop   = (const int*)d_in[5];
    const int*   flipb     = (const int*)d_in[6];
    const int*   rot_k     = (const int*)d_in[7];

    float* out = (float*)d_out;

    aug_fused_kernel<<<dim3(512), dim3(256), 0, stream>>>(
        crops, off_frac, crop_size, do_crop, flipb, rot_k, bright, contrast, out);
}

// Round 11
// 201.519 us; speedup vs baseline: 1.1321x; 1.1321x over previous
//
#include <hip/hip_runtime.h>
#include <math.h>

#define SDIM 256
#define CH 5
#define ROWF (SDIM * CH)      // 1280 floats per image row
#define GRAYF 0.9999f         // 0.2989+0.5870+0.1140
// d_ws layout (floats): part[64 images][64 blocks][CH]

// ============ K2: resample+flip+rot, RAW output + per-block channel partials ============
__global__ __launch_bounds__(256) void aug_out_kernel(
    const float* __restrict__ crops,
    const float* __restrict__ off_frac,
    const int*   __restrict__ crop_size,
    const int*   __restrict__ do_crop,
    const int*   __restrict__ flip,
    const int*   __restrict__ rot_k,
    float* __restrict__ part,     // [64][64][CH] written, not accumulated
    float* __restrict__ out)
{
    const int gid  = blockIdx.x;       // row-group 0..63
    const int oi0  = gid * 4;          // first output row of this block
    const int b    = blockIdx.y;
    const int tid  = threadIdx.x;
    const int rr   = tid >> 6;         // output row within block (wave-uniform)
    const int lane = tid & 63;         // lane owns pixels lane+64p, p=0..3

    // union: even-k stage 5*1280 | odd-k stage 28*260 | obuf 4*1280
    __shared__ __align__(16) float smem[28 * 260];
    __shared__ float psum[4][CH];

    const bool  docrop = do_crop[b] != 0;
    const float size_f = docrop ? (float)crop_size[b] : 256.0f;
    const float scale  = size_f * (1.0f / 256.0f);
    const float span   = 256.0f - size_f + 1.0f;
    const float off0   = docrop ? floorf(off_frac[2 * b + 0] * span) : 0.0f;
    const float off1   = docrop ? floorf(off_frac[2 * b + 1] * span) : 0.0f;
    const int   k      = rot_k[b] & 3;
    const bool  flp    = flip[b] != 0;

    float vout[20];   // RAW resampled values; vout[p*5+ch] for pixel oj = lane + 64p

    if ((k & 1) == 0) {
        // ---- even k: src row <- oi (wave-uniform), src col <- oj ----
        const int y_min = (k == 0) ? oi0 : 255 - (oi0 + 3);
        const float cymin = ((float)y_min + 0.5f) * scale - 0.5f + off0;
        const int rbase = (int)floorf(cymin);
        const int nst   = docrop ? 5 : 4;    // staged input rows

        const float4* src4 = reinterpret_cast<const float4*>(crops + (size_t)b * SDIM * ROWF);
        float4* dst4 = reinterpret_cast<float4*>(smem);
        for (int i = tid; i < nst * 320; i += 256) {
            const int w  = i / 320;
            const int f4 = i - w * 320;
            const int rc = min(max(rbase + w, 0), 255);
            dst4[i] = src4[rc * 320 + f4];
        }
        __syncthreads();

        const int oi = oi0 + rr;
        const int y  = (k == 0) ? oi : 255 - oi;

        if (!docrop) {
            // exact permutation: fy=0, fx=0, row y staged at slot y-rbase
            const float* rb = smem + (y - rbase) * ROWF;
            #pragma unroll
            for (int p = 0; p < 4; ++p) {
                const int oj = lane + 64 * p;
                const int xf = (k == 0) ? oj : 255 - oj;
                const int x  = flp ? 255 - xf : xf;
                #pragma unroll
                for (int ch = 0; ch < CH; ++ch) vout[p * 5 + ch] = rb[x * CH + ch];
            }
        } else {
            const float cy  = ((float)y + 0.5f) * scale - 0.5f + off0;
            const float flr = floorf(cy);
            const float fy  = cy - flr;
            const float* rbA = smem + ((int)flr - rbase) * ROWF;
            const float* rbB = rbA + ROWF;
            #pragma unroll
            for (int p = 0; p < 4; ++p) {
                const int oj = lane + 64 * p;
                const int xf = (k == 0) ? oj : 255 - oj;
                const int x  = flp ? 255 - xf : xf;
                const float cx  = ((float)x + 0.5f) * scale - 0.5f + off1;
                const float fl2 = floorf(cx);
                const float fx  = cx - fl2;
                const int c0 = min(max((int)fl2, 0), 255);
                const int c1 = min(max((int)fl2 + 1, 0), 255);
                #pragma unroll
                for (int ch = 0; ch < CH; ++ch) {
                    const float aV = rbA[c0 * CH + ch] + fx * (rbA[c1 * CH + ch] - rbA[c0 * CH + ch]);
                    const float dV = rbB[c0 * CH + ch] + fx * (rbB[c1 * CH + ch] - rbB[c0 * CH + ch]);
                    vout[p * 5 + ch] = aV + fy * (dV - aV);
                }
            }
        }
    } else {
        // ---- odd k: src col <- oi (wave-uniform), src row <- oj ----
        const int xfA = (k == 1) ? 255 - oi0 : oi0;
        const int xfB = (k == 1) ? 255 - (oi0 + 3) : oi0 + 3;
        const int xA = flp ? 255 - xfA : xfA;
        const int xB = flp ? 255 - xfB : xfB;
        const int xmin = min(xA, xB);

        if (!docrop) {
            // exact permutation: stage 24-float col window (6 float4/row)
            const int base4 = min((xmin * CH) & ~3, ROWF - 24);
            const float4* rp = reinterpret_cast<const float4*>(
                crops + ((size_t)b * SDIM + tid) * ROWF + base4);
            const float4 q0 = rp[0], q1 = rp[1], q2 = rp[2];
            const float4 q3 = rp[3], q4 = rp[4], q5 = rp[5];
            smem[ 0*260+tid]=q0.x; smem[ 1*260+tid]=q0.y; smem[ 2*260+tid]=q0.z; smem[ 3*260+tid]=q0.w;
            smem[ 4*260+tid]=q1.x; smem[ 5*260+tid]=q1.y; smem[ 6*260+tid]=q1.z; smem[ 7*260+tid]=q1.w;
            smem[ 8*260+tid]=q2.x; smem[ 9*260+tid]=q2.y; smem[10*260+tid]=q2.z; smem[11*260+tid]=q2.w;
            smem[12*260+tid]=q3.x; smem[13*260+tid]=q3.y; smem[14*260+tid]=q3.z; smem[15*260+tid]=q3.w;
            smem[16*260+tid]=q4.x; smem[17*260+tid]=q4.y; smem[18*260+tid]=q4.z; smem[19*260+tid]=q4.w;
            smem[20*260+tid]=q5.x; smem[21*260+tid]=q5.y; smem[22*260+tid]=q5.z; smem[23*260+tid]=q5.w;
            __syncthreads();

            const int oi = oi0 + rr;
            const int xf = (k == 1) ? 255 - oi : oi;
            const int x  = flp ? 255 - xf : xf;
            const int slotA = x * CH - base4;
            #pragma unroll
            for (int p = 0; p < 4; ++p) {
                const int oj = lane + 64 * p;
                const int y  = (k == 1) ? oj : 255 - oj;
                #pragma unroll
                for (int ch = 0; ch < CH; ++ch)
                    vout[p * 5 + ch] = smem[(slotA + ch) * 260 + y];
            }
        } else {
            const float cxmin = ((float)xmin + 0.5f) * scale - 0.5f + off1;
            const int cbase = (int)floorf(cxmin);
            const int base4 = (cbase * CH) & ~3;
            const bool fastp = (cbase >= 0) && (cbase + 4 <= 255) && (base4 >= 0) && (base4 + 28 <= ROWF);

            if (fastp) {
                const float4* rp = reinterpret_cast<const float4*>(
                    crops + ((size_t)b * SDIM + tid) * ROWF + base4);
                const float4 q0 = rp[0], q1 = rp[1], q2 = rp[2], q3 = rp[3];
                const float4 q4 = rp[4], q5 = rp[5], q6 = rp[6];
                smem[ 0*260+tid]=q0.x; smem[ 1*260+tid]=q0.y; smem[ 2*260+tid]=q0.z; smem[ 3*260+tid]=q0.w;
                smem[ 4*260+tid]=q1.x; smem[ 5*260+tid]=q1.y; smem[ 6*260+tid]=q1.z; smem[ 7*260+tid]=q1.w;
                smem[ 8*260+tid]=q2.x; smem[ 9*260+tid]=q2.y; smem[10*260+tid]=q2.z; smem[11*260+tid]=q2.w;
                smem[12*260+tid]=q3.x; smem[13*260+tid]=q3.y; smem[14*260+tid]=q3.z; smem[15*260+tid]=q3.w;
                smem[16*260+tid]=q4.x; smem[17*260+tid]=q4.y; smem[18*260+tid]=q4.z; smem[19*260+tid]=q4.w;
                smem[20*260+tid]=q5.x; smem[21*260+tid]=q5.y; smem[22*260+tid]=q5.z; smem[23*260+tid]=q5.w;
                smem[24*260+tid]=q6.x; smem[25*260+tid]=q6.y; smem[26*260+tid]=q6.z; smem[27*260+tid]=q6.w;
            } else {
                #pragma unroll
                for (int w = 0; w < 28; ++w) {
                    const int f2 = base4 + w + ROWF;       // bias keeps div positive
                    const int c2 = f2 / 5;
                    const int ch = f2 - c2 * 5;
                    const int cc = min(max(c2 - 256, 0), 255);
                    smem[w * 260 + tid] = crops[((size_t)b * SDIM + tid) * ROWF + cc * CH + ch];
                }
            }
            __syncthreads();

            const int oi = oi0 + rr;
            const int xf = (k == 1) ? 255 - oi : oi;
            const int x  = flp ? 255 - xf : xf;
            const float cx  = ((float)x + 0.5f) * scale - 0.5f + off1;
            const float fl2 = floorf(cx);
            const float fx  = cx - fl2;
            const int slotA = (int)fl2 * CH - base4;   // pre-clamp slot; content clamped
            const int slotB = slotA + CH;

            #pragma unroll
            for (int p = 0; p < 4; ++p) {
                const int oj = lane + 64 * p;
                const int y  = (k == 1) ? oj : 255 - oj;
                const float cy  = ((float)y + 0.5f) * scale - 0.5f + off0;
                const float flr = floorf(cy);
                const float fy  = cy - flr;
                const int r0 = min(max((int)flr, 0), 255);
                const int r1 = min(max((int)flr + 1, 0), 255);
                #pragma unroll
                for (int ch = 0; ch < CH; ++ch) {
                    const float p00 = smem[(slotA + ch) * 260 + r0];
                    const float p01 = smem[(slotB + ch) * 260 + r0];
                    const float p10 = smem[(slotA + ch) * 260 + r1];
                    const float p11 = smem[(slotB + ch) * 260 + r1];
                    const float aV = p00 + fx * (p01 - p00);
                    const float dV = p10 + fx * (p11 - p10);
                    vout[p * 5 + ch] = aV + fy * (dV - aV);
                }
            }
        }
    }

    // ---- per-block channel partials over this block's 1024 output pixels ----
    {
        const int wv = tid >> 6;
        #pragma unroll
        for (int ch = 0; ch < CH; ++ch) {
            float s = vout[ch] + vout[5 + ch] + vout[10 + ch] + vout[15 + ch];
            #pragma unroll
            for (int o = 32; o > 0; o >>= 1) s += __shfl_down(s, o, 64);
            if (lane == 0) psum[wv][ch] = s;
        }
    }

    // ---- repack RAW v through LDS (stride-5 writes: conflict-free) + dense stores ----
    __syncthreads();   // staging done (reuse smem as obuf) + psum published
    if (tid == 0) {
        #pragma unroll
        for (int ch = 0; ch < CH; ++ch)
            part[((size_t)b * 64 + gid) * CH + ch] =
                psum[0][ch] + psum[1][ch] + psum[2][ch] + psum[3][ch];
    }
    #pragma unroll
    for (int p = 0; p < 4; ++p) {
        const int oj = lane + 64 * p;
        #pragma unroll
        for (int ch = 0; ch < CH; ++ch)
            smem[rr * ROWF + oj * CH + ch] = vout[p * 5 + ch];
    }
    __syncthreads();

    const float4* ob4 = reinterpret_cast<const float4*>(smem);
    float4* dst = reinterpret_cast<float4*>(out + ((size_t)b * SDIM + oi0) * ROWF);
    #pragma unroll
    for (int q = 0; q < 5; ++q) dst[q * 256 + tid] = ob4[q * 256 + tid];
}

// ============ K3: dense in-place affine over the raw output ============
// out = v*aa[ch] + ab[ch]; thread handles 20 consecutive floats (4 pixels),
// so the channel map is static (20 = lcm(4,5)).
__global__ __launch_bounds__(256) void aug_affine_kernel(
    const float* __restrict__ part,
    const float* __restrict__ bright,
    const float* __restrict__ contrast,
    float* __restrict__ out)
{
    const int g   = blockIdx.x;   // row-group 0..63 (4 rows)
    const int b   = blockIdx.y;
    const int tid = threadIdx.x;

    __shared__ float pbuf[64][CH];
    __shared__ float prm[2 * CH];

    if (tid < 64) {
        const float* pp = part + ((size_t)b * 64 + tid) * CH;
        #pragma unroll
        for (int ch = 0; ch < CH; ++ch) pbuf[tid][ch] = pp[ch];
    }
    __syncthreads();
    if (tid < CH) {
        float s = 0.0f;
        #pragma unroll
        for (int j = 0; j < 64; ++j) s += pbuf[j][tid];
        const float m  = s * (1.0f / 65536.0f);
        const float co = contrast[b * CH + tid];
        const float br = bright[b * CH + tid];
        prm[tid]      = co * GRAYF;
        prm[CH + tid] = ((1.0f - co) * m + br) * GRAYF;
    }
    __syncthreads();

    float aa[5], ab[5];
    #pragma unroll
    for (int ch = 0; ch < CH; ++ch) { aa[ch] = prm[ch]; ab[ch] = prm[CH + ch]; }

    float4* p4 = reinterpret_cast<float4*>(
        out + ((size_t)b * SDIM + g * 4) * ROWF + tid * 20);
    float4 q0 = p4[0], q1 = p4[1], q2 = p4[2], q3 = p4[3], q4 = p4[4];
    // float j of the 20-chunk has channel j%5 (chunk start % 5 == 0):
    q0.x = q0.x*aa[0]+ab[0]; q0.y = q0.y*aa[1]+ab[1]; q0.z = q0.z*aa[2]+ab[2]; q0.w = q0.w*aa[3]+ab[3];
    q1.x = q1.x*aa[4]+ab[4]; q1.y = q1.y*aa[0]+ab[0]; q1.z = q1.z*aa[1]+ab[1]; q1.w = q1.w*aa[2]+ab[2];
    q2.x = q2.x*aa[3]+ab[3]; q2.y = q2.y*aa[4]+ab[4]; q2.z = q2.z*aa[0]+ab[0]; q2.w = q2.w*aa[1]+ab[1];
    q3.x = q3.x*aa[2]+ab[2]; q3.y = q3.y*aa[3]+ab[3]; q3.z = q3.z*aa[4]+ab[4]; q3.w = q3.w*aa[0]+ab[0];
    q4.x = q4.x*aa[1]+ab[1]; q4.y = q4.y*aa[2]+ab[2]; q4.z = q4.z*aa[3]+ab[3]; q4.w = q4.w*aa[4]+ab[4];
    p4[0] = q0; p4[1] = q1; p4[2] = q2; p4[3] = q3; p4[4] = q4;
}

extern "C" void kernel_launch(void* const* d_in, const int* in_sizes, int n_in,
                              void* d_out, int out_size, void* d_ws, size_t ws_size,
                              hipStream_t stream) {
    const float* crops     = (const float*)d_in[0];
    const float* off_frac  = (const float*)d_in[1];
    const float* bright    = (const float*)d_in[2];
    const float* contrast  = (const float*)d_in[3];
    const int*   crop_size = (const int*)d_in[4];
    const int*   do_crop   = (const int*)d_in[5];
    const int*   flipb     = (const int*)d_in[6];
    const int*   rot_k     = (const int*)d_in[7];

    float* out  = (float*)d_out;
    float* part = (float*)d_ws;   // [64][64][CH], fully written by K2 each call

    dim3 blk(256);
    aug_out_kernel<<<dim3(64, 64), blk, 0, stream>>>(crops, off_frac, crop_size, do_crop,
                                                     flipb, rot_k, part, out);
    aug_affine_kernel<<<dim3(64, 64), blk, 0, stream>>>(part, bright, contrast, out);
}